// Round 12
// baseline (640.341 us; speedup 1.0000x reference)
//
#include <hip/hip_runtime.h>

// ================= degree + packed (dst,rank) =================

__global__ void k_count(const int* __restrict__ dst, int* __restrict__ cnt,
                        unsigned int* __restrict__ pack, int e) {
    int i = blockIdx.x * blockDim.x + threadIdx.x;
    if (i < e) {
        int d = dst[i];
        int r = atomicAdd(&cnt[d], 1);
        pack[i] = ((unsigned int)d << 14) | (unsigned int)r;   // deg < 2^14 guaranteed
    }
}

// ---- single-block fused scan: cnt -> rowptr + dinv ----
__global__ void k_scan1(const int* __restrict__ cnt, int* __restrict__ rowptr,
                        float* __restrict__ dinv, int n) {
    __shared__ int sm[1024];
    int t = threadIdx.x;
    int chunk = (n + 1023) >> 10;
    int b = t * chunk, e = min(b + chunk, n);
    int s = 0;
    for (int i = b; i < e; ++i) s += cnt[i];
    sm[t] = s;
    __syncthreads();
    for (int off = 1; off < 1024; off <<= 1) {
        int v = (t >= off) ? sm[t - off] : 0;
        __syncthreads();
        sm[t] += v;
        __syncthreads();
    }
    int run = t ? sm[t - 1] : 0;
    for (int i = b; i < e; ++i) {
        rowptr[i] = run;
        dinv[i] = rsqrtf((float)(cnt[i] + 1));   // +1 self-loop
        run += cnt[i];
    }
    if (t == 1023) rowptr[n] = run;
}

// ================= FUSED: XCD-partitioned CSR fill  ||  GEMM<128> =================

#define FILL_G 192

__device__ __forceinline__ void fill_role(const int* __restrict__ src,
                                          const unsigned int* __restrict__ pack,
                                          const int* __restrict__ rowptr,
                                          int* __restrict__ csr_src,
                                          int e, float scale, int r, int g) {
    int chunk = (e + FILL_G - 1) / FILL_G;
    int beg = g * chunk, end = min(beg + chunk, e);
    for (int i = beg + threadIdx.x; i < end; i += blockDim.x) {
        unsigned int p = pack[i];
        int d = (int)(p >> 14);
        if ((int)((float)d * scale) == r) {
            int pos = rowptr[d] + (int)(p & 0x3FFFu);
            __builtin_nontemporal_store(src[i], &csr_src[pos]);
        }
    }
}

__global__ __launch_bounds__(256) void k_fuse(
        const int* __restrict__ src, const unsigned int* __restrict__ pack,
        const int* __restrict__ rowptr, int* __restrict__ csr_src, int e, float scale,
        const float* __restrict__ A, const float* __restrict__ W,
        const float* __restrict__ dinv, float* __restrict__ C, int n) {
    const int BM = 128, BK = 32, COUT = 128, TN = 8;
    __shared__ float sA[BM * BK];
    __shared__ float sW[BK * COUT];

    int t8 = blockIdx.x >> 3, l = blockIdx.x & 7;
    int m = t8 % 3, q = t8 / 3;

    if (m < 2) {
        int g = q * 2 + m;
        if (g < FILL_G)
            fill_role(src, pack, rowptr, csr_src, e, scale, l, g);
        return;
    }

    int bid = q * 8 + l;
    int row0 = bid * BM;
    if (row0 >= n) return;

    int tid = threadIdx.x;
    int lane = tid & 63;
    int wv = tid >> 6;
    int tr = tid & 15, tc = tid >> 4;
    int c0 = tc * TN;

    float acc[8][TN];
#pragma unroll
    for (int i = 0; i < 8; ++i)
#pragma unroll
        for (int j = 0; j < TN; ++j) acc[i][j] = 0.f;

    for (int slab = 0; slab < 4; ++slab) {
        if (slab) __syncthreads();

#pragma unroll
        for (int it = 0; it < 4; ++it) {
            int chunk = it * 4 + wv;
            int L = chunk * 64 + lane;
            int row = L >> 3;
            int gp = L & 7;
            int gsrc = gp ^ ((row >> 3) & 7);
            int grow = min(row0 + row, n - 1);
            const float* srcp = A + (long)grow * 128 + slab * 32 + gsrc * 4;
            float* dstp = sA + chunk * 256;
            __builtin_amdgcn_global_load_lds(
                (const __attribute__((address_space(1))) void*)srcp,
                (__attribute__((address_space(3))) void*)dstp, 16, 0, 0);
        }
#pragma unroll
        for (int it = 0; it < 4; ++it) {
            int chunk = it * 4 + wv;
            int L = chunk * 64 + lane;
            int k = L >> 5;
            int gp = L & 31;
            const float* srcp = W + (long)(slab * 32 + k) * COUT + gp * 4;
            float* dstp = sW + chunk * 256;
            __builtin_amdgcn_global_load_lds(
                (const __attribute__((address_space(1))) void*)srcp,
                (__attribute__((address_space(3))) void*)dstp, 16, 0, 0);
        }
        __syncthreads();

#pragma unroll
        for (int k4 = 0; k4 < 8; ++k4) {
            int slot = k4 ^ (tr & 7);
            float4 a4[8];
#pragma unroll
            for (int i = 0; i < 8; ++i)
                a4[i] = *reinterpret_cast<const float4*>(&sA[(tr * 8 + i) * 32 + slot * 4]);
#pragma unroll
            for (int kk = 0; kk < 4; ++kk) {
                float w[TN];
#pragma unroll
                for (int j = 0; j < TN; j += 4)
                    *reinterpret_cast<float4*>(&w[j]) =
                        *reinterpret_cast<const float4*>(&sW[(k4 * 4 + kk) * COUT + c0 + j]);
#pragma unroll
                for (int i = 0; i < 8; ++i) {
                    float av = (kk == 0) ? a4[i].x : (kk == 1) ? a4[i].y
                             : (kk == 2) ? a4[i].z : a4[i].w;
#pragma unroll
                    for (int j = 0; j < TN; ++j)
                        acc[i][j] = fmaf(av, w[j], acc[i][j]);
                }
            }
        }
    }

#pragma unroll
    for (int i = 0; i < 8; ++i) {
        int row = row0 + tr * 8 + i;
        if (row < n) {
            float dv = dinv[row];
#pragma unroll
            for (int j = 0; j < TN; ++j) acc[i][j] *= dv;
            *reinterpret_cast<float4*>(C + (long)row * COUT + c0) =
                *reinterpret_cast<float4*>(&acc[i][0]);
            *reinterpret_cast<float4*>(C + (long)row * COUT + c0 + 4) =
                *reinterpret_cast<float4*>(&acc[i][4]);
        }
    }
}

// ================= GEMM<64> body (shared by standalone + fused) =================

__device__ __forceinline__ void gemm64_body(const float* __restrict__ A,
                                            const float* __restrict__ W,
                                            const float* __restrict__ dinv,
                                            float* __restrict__ C, int n, int row0) {
    const int BK = 32, COUT = 64, TN = 4;
    __shared__ float sA[128 * BK];            // 16 KB
    __shared__ float sW[BK * COUT];           // 8 KB

    int tid = threadIdx.x;
    int lane = tid & 63;
    int wv = tid >> 6;
    int tr = tid & 15, tc = tid >> 4;
    int c0 = tc * TN;

    float acc[8][TN];
#pragma unroll
    for (int i = 0; i < 8; ++i)
#pragma unroll
        for (int j = 0; j < TN; ++j) acc[i][j] = 0.f;

    for (int slab = 0; slab < 4; ++slab) {
        if (slab) __syncthreads();

#pragma unroll
        for (int it = 0; it < 4; ++it) {
            int chunk = it * 4 + wv;
            int L = chunk * 64 + lane;
            int row = L >> 3;
            int gp = L & 7;
            int gsrc = gp ^ ((row >> 3) & 7);
            int grow = min(row0 + row, n - 1);
            const float* srcp = A + (long)grow * 128 + slab * 32 + gsrc * 4;
            float* dstp = sA + chunk * 256;
            __builtin_amdgcn_global_load_lds(
                (const __attribute__((address_space(1))) void*)srcp,
                (__attribute__((address_space(3))) void*)dstp, 16, 0, 0);
        }
#pragma unroll
        for (int it = 0; it < 2; ++it) {
            int chunk = it * 4 + wv;
            int L = chunk * 64 + lane;
            int k = L >> 4;
            int gp = L & 15;
            const float* srcp = W + (long)(slab * 32 + k) * COUT + gp * 4;
            float* dstp = sW + chunk * 256;
            __builtin_amdgcn_global_load_lds(
                (const __attribute__((address_space(1))) void*)srcp,
                (__attribute__((address_space(3))) void*)dstp, 16, 0, 0);
        }
        __syncthreads();

#pragma unroll
        for (int k4 = 0; k4 < 8; ++k4) {
            int slot = k4 ^ (tr & 7);
            float4 a4[8];
#pragma unroll
            for (int i = 0; i < 8; ++i)
                a4[i] = *reinterpret_cast<const float4*>(&sA[(tr * 8 + i) * 32 + slot * 4]);
#pragma unroll
            for (int kk = 0; kk < 4; ++kk) {
                float w[TN];
                *reinterpret_cast<float4*>(&w[0]) =
                    *reinterpret_cast<const float4*>(&sW[(k4 * 4 + kk) * COUT + c0]);
#pragma unroll
                for (int i = 0; i < 8; ++i) {
                    float av = (kk == 0) ? a4[i].x : (kk == 1) ? a4[i].y
                             : (kk == 2) ? a4[i].z : a4[i].w;
#pragma unroll
                    for (int j = 0; j < TN; ++j)
                        acc[i][j] = fmaf(av, w[j], acc[i][j]);
                }
            }
        }
    }

#pragma unroll
    for (int i = 0; i < 8; ++i) {
        int row = row0 + tr * 8 + i;
        if (row < n) {
            float dv = dinv[row];
#pragma unroll
            for (int j = 0; j < TN; ++j) acc[i][j] *= dv;
            *reinterpret_cast<float4*>(C + (long)row * COUT + c0) =
                *reinterpret_cast<float4*>(&acc[i][0]);
        }
    }
}

__global__ __launch_bounds__(256) void k_gemm64(const float* __restrict__ A,
                                                const float* __restrict__ W,
                                                const float* __restrict__ dinv,
                                                float* __restrict__ C, int n, int rowbase) {
    gemm64_body(A, W, dinv, C, n, rowbase + blockIdx.x * 128);
}

// ================= gather body (shared) =================

template<int C, bool RELU>
__device__ __forceinline__ void gather_node(const int* __restrict__ rowptr,
                                            const int* __restrict__ csr_src,
                                            const float* __restrict__ dinv,
                                            const float* __restrict__ h,
                                            const float* __restrict__ bias,
                                            float* __restrict__ out, int node, int c) {
    const float4* h4 = reinterpret_cast<const float4*>(h);
    float4 acc = h4[((long)node * C + c) >> 2];   // self-loop (already dinv-scaled)

    int beg = rowptr[node], end = rowptr[node + 1];
    int e = beg;
    for (; e + 8 <= end; e += 8) {
        int s[8];
#pragma unroll
        for (int q = 0; q < 8; ++q) s[q] = csr_src[e + q];
        float4 u[8];
#pragma unroll
        for (int q = 0; q < 8; ++q) u[q] = h4[((long)s[q] * C + c) >> 2];
        float sx0 = (u[0].x + u[1].x) + (u[2].x + u[3].x);
        float sx1 = (u[4].x + u[5].x) + (u[6].x + u[7].x);
        float sy0 = (u[0].y + u[1].y) + (u[2].y + u[3].y);
        float sy1 = (u[4].y + u[5].y) + (u[6].y + u[7].y);
        float sz0 = (u[0].z + u[1].z) + (u[2].z + u[3].z);
        float sz1 = (u[4].z + u[5].z) + (u[6].z + u[7].z);
        float sw0 = (u[0].w + u[1].w) + (u[2].w + u[3].w);
        float sw1 = (u[4].w + u[5].w) + (u[6].w + u[7].w);
        acc.x += sx0 + sx1; acc.y += sy0 + sy1;
        acc.z += sz0 + sz1; acc.w += sw0 + sw1;
    }
    for (; e < end; ++e) {
        int s = csr_src[e];
        float4 u = h4[((long)s * C + c) >> 2];
        acc.x += u.x; acc.y += u.y; acc.z += u.z; acc.w += u.w;
    }
    float dd = dinv[node];
    float4 b4 = *reinterpret_cast<const float4*>(bias + c);
    acc.x = fmaf(acc.x, dd, b4.x);
    acc.y = fmaf(acc.y, dd, b4.y);
    acc.z = fmaf(acc.z, dd, b4.z);
    acc.w = fmaf(acc.w, dd, b4.w);
    if (RELU) {
        acc.x = fmaxf(acc.x, 0.f); acc.y = fmaxf(acc.y, 0.f);
        acc.z = fmaxf(acc.z, 0.f); acc.w = fmaxf(acc.w, 0.f);
    }
    *reinterpret_cast<float4*>(out + (long)node * C + c) = acc;
}

template<int C, bool RELU>
__global__ void k_gather(const int* __restrict__ rowptr, const int* __restrict__ csr_src,
                         const float* __restrict__ dinv, const float* __restrict__ h,
                         const float* __restrict__ bias, float* __restrict__ out,
                         int nbeg, int nend) {
    const int TPN = C / 4;
    int t = blockIdx.x * blockDim.x + threadIdx.x;
    int node = nbeg + t / TPN;
    if (node >= nend) return;
    gather_node<C, RELU>(rowptr, csr_src, dinv, h, bias, out, node, (t % TPN) * 4);
}

// ================= FUSED-2: gather128 part B  ||  gemm64 part A =================
// gemm64-A reads h rows [0,H1) (written by the prior gather128-A dispatch) and
// writes z rows [0,H1) (separate buffer). gather-B reads all of h-tilde and
// writes h rows [H1,n). Disjoint regions; both only need prior dispatches.

__global__ __launch_bounds__(256) void k_fuse2(
        const int* __restrict__ rowptr, const int* __restrict__ csr_src,
        const float* __restrict__ dinv, const float* __restrict__ ht,
        const float* __restrict__ b1, float* __restrict__ h,
        const float* __restrict__ W2, float* __restrict__ z,
        int n, int H1, int NG64) {
    if ((int)blockIdx.x < NG64) {
        gemm64_body(h, W2, dinv, z, n, blockIdx.x * 128);   // rows [0,H1)
        return;
    }
    int g = blockIdx.x - NG64;
    int node = H1 + g * 8 + (threadIdx.x >> 5);
    if (node < n)
        gather_node<128, true>(rowptr, csr_src, dinv, ht, b1, h, node, (threadIdx.x & 31) * 4);
}

// ================= decode =================

__global__ void k_decode(const int* __restrict__ ia, const int* __restrict__ ib,
                         const float* __restrict__ z, float* __restrict__ out, int m) {
    int t = blockIdx.x * blockDim.x + threadIdx.x;
    int k = t / 16;
    if (k >= m) return;
    int c = (t & 15) * 4;
    int a = ia[k], b = ib[k];
    float4 va = *reinterpret_cast<const float4*>(z + (long)a * 64 + c);
    float4 vb = *reinterpret_cast<const float4*>(z + (long)b * 64 + c);
    float dot = va.x * vb.x + va.y * vb.y + va.z * vb.z + va.w * vb.w;
    dot += __shfl_xor(dot, 8);
    dot += __shfl_xor(dot, 4);
    dot += __shfl_xor(dot, 2);
    dot += __shfl_xor(dot, 1);
    if ((t & 15) == 0) out[k] = dot;
}

// ================= launcher =================

extern "C" void kernel_launch(void* const* d_in, const int* in_sizes, int n_in,
                              void* d_out, int out_size, void* d_ws, size_t ws_size,
                              hipStream_t stream) {
    const float* x  = (const float*)d_in[0];
    const int*   ei = (const int*)d_in[1];
    const int*   el = (const int*)d_in[2];
    const float* W1 = (const float*)d_in[3];
    const float* b1 = (const float*)d_in[4];
    const float* W2 = (const float*)d_in[5];
    const float* b2 = (const float*)d_in[6];
    float* out = (float*)d_out;

    const int N = in_sizes[0] / 128;
    const int E = in_sizes[1] / 2;
    const int L = out_size;

    const int* src = ei;
    const int* dst = ei + E;
    const int* la  = el;
    const int* lb  = el + L;

    auto cdiv = [](long a, long b) { return (int)((a + b - 1) / b); };

    // pipelined layout needs: bufA + bufB + z + csr + cnt + rowptr + dinv
    size_t need = ((size_t)N * 128 * 2 + (size_t)N * 64) * 4 + (size_t)E * 4
                + ((size_t)N * 3 + 8) * 4;
    bool pipelined = (ws_size >= need);

    float* bufA = (float*)d_ws;                     // N*128 h-tilde
    float* bufB = bufA + (long)N * 128;             // N*128 h (pack overlays pre-fuse)
    float* z;
    int*   csr_src;
    if (pipelined) {
        z = bufB + (long)N * 128;                   // N*64 separate
        csr_src = (int*)(z + (long)N * 64);
    } else {
        z = bufA;                                   // serial fallback (R11 layout)
        csr_src = (int*)(bufB + (long)N * 128);
    }
    int*   cnt    = csr_src + E;                    // N
    int*   rowptr = cnt + N;                        // N+1
    float* dinv   = (float*)(rowptr + N + 1);       // N
    unsigned int* pack = (unsigned int*)bufB;       // E u32 (dies at end of k_fuse)
    float* zout = pipelined ? bufA : (bufA + (long)N * 64);  // N*64

    // ---- CSR build + normalization ----
    hipMemsetAsync(cnt, 0, (size_t)N * sizeof(int), stream);
    k_count<<<cdiv(E, 256), 256, 0, stream>>>(dst, cnt, pack, E);
    k_scan1<<<1, 1024, 0, stream>>>(cnt, rowptr, dinv, N);

    // ---- fused: CSR fill || layer-1 GEMM ----
    k_fuse<<<294 * 8, 256, 0, stream>>>(src, pack, rowptr, csr_src, E, 8.0f / (float)N,
                                        x, W1, dinv, bufA, N);

    if (pipelined) {
        const int H1 = ((N / 2 + 127) / 128) * 128;     // 50048
        const int NG64 = H1 / 128;                      // 391
        const int NB2 = cdiv(N - H1, 8);
        // gather128 part A: h rows [0,H1)
        k_gather<128, true><<<cdiv((long)H1 * 32, 256), 256, 0, stream>>>(
            rowptr, csr_src, dinv, bufA, b1, bufB, 0, H1);
        // fused: gather128 part B || gemm64 part A
        k_fuse2<<<NG64 + NB2, 256, 0, stream>>>(rowptr, csr_src, dinv, bufA, b1, bufB,
                                                W2, z, N, H1, NG64);
        // gemm64 part B: rows [H1,N)
        k_gemm64<<<cdiv(N - H1, 128), 256, 0, stream>>>(bufB, W2, dinv, z, N, H1);
    } else {
        k_gather<128, true><<<cdiv((long)N * 32, 256), 256, 0, stream>>>(
            rowptr, csr_src, dinv, bufA, b1, bufB, 0, N);
        k_gemm64<<<cdiv(N, 128), 256, 0, stream>>>(bufB, W2, dinv, z, N, 0);
    }

    // ---- layer 2 aggregation + decode ----
    k_gather<64, false><<<cdiv((long)N * 16, 256), 256, 0, stream>>>(
        rowptr, csr_src, dinv, z, b2, zout, 0, N);
    k_decode<<<cdiv((long)L * 16, 256), 256, 0, stream>>>(la, lb, zout, out, L);
}

// Round 13
// 482.265 us; speedup vs baseline: 1.3278x; 1.3278x over previous
//
#include <hip/hip_runtime.h>

// ================= degree + packed (dst,rank) =================

__global__ void k_count(const int* __restrict__ dst, int* __restrict__ cnt,
                        unsigned int* __restrict__ pack, int e) {
    int i = blockIdx.x * blockDim.x + threadIdx.x;
    if (i < e) {
        int d = dst[i];
        int r = atomicAdd(&cnt[d], 1);
        pack[i] = ((unsigned int)d << 14) | (unsigned int)r;   // deg < 2^14 guaranteed
    }
}

// ---- 3-phase parallel scan: cnt -> rowptr (+ dinv fused) ----
#define SCP 1024

__global__ void k_scan_a(const int* __restrict__ cnt, int* __restrict__ part, int n) {
    int p = blockIdx.x * blockDim.x + threadIdx.x;
    if (p >= SCP) return;
    int chunk = (n + SCP - 1) / SCP;
    int b = p * chunk, e = min(b + chunk, n), s = 0;
    for (int i = b; i < e; ++i) s += cnt[i];
    part[p] = s;
}

__global__ void k_scan_b(int* __restrict__ part) {   // 1 block, 1024 threads
    __shared__ int sm[SCP];
    int t = threadIdx.x;
    sm[t] = part[t];
    __syncthreads();
    for (int off = 1; off < SCP; off <<= 1) {
        int v = (t >= off) ? sm[t - off] : 0;
        __syncthreads();
        sm[t] += v;
        __syncthreads();
    }
    part[t] = t ? sm[t - 1] : 0;   // exclusive
}

__global__ void k_scan_c(const int* __restrict__ cnt, const int* __restrict__ part,
                         int* __restrict__ rowptr, float* __restrict__ dinv, int n) {
    int p = blockIdx.x * blockDim.x + threadIdx.x;
    if (p >= SCP) return;
    int chunk = (n + SCP - 1) / SCP;
    int b = p * chunk, e = min(b + chunk, n);
    int run = part[p];
    for (int i = b; i < e; ++i) {
        rowptr[i] = run;
        dinv[i] = rsqrtf((float)(cnt[i] + 1));   // +1 self-loop
        run += cnt[i];
    }
    if (p == SCP - 1) rowptr[n] = run;
}

// ================= FUSED: XCD-partitioned CSR fill  ||  GEMM<128> =================

#define FILL_G 192

__device__ __forceinline__ void fill_role(const int* __restrict__ src,
                                          const unsigned int* __restrict__ pack,
                                          const int* __restrict__ rowptr,
                                          int* __restrict__ csr_src,
                                          int e, float scale, int r, int g) {
    int chunk = (e + FILL_G - 1) / FILL_G;
    int beg = g * chunk, end = min(beg + chunk, e);
    for (int i = beg + threadIdx.x; i < end; i += blockDim.x) {
        unsigned int p = pack[i];
        int d = (int)(p >> 14);
        if ((int)((float)d * scale) == r) {
            int pos = rowptr[d] + (int)(p & 0x3FFFu);
            __builtin_nontemporal_store(src[i], &csr_src[pos]);
        }
    }
}

__global__ __launch_bounds__(256) void k_fuse(
        const int* __restrict__ src, const unsigned int* __restrict__ pack,
        const int* __restrict__ rowptr, int* __restrict__ csr_src, int e, float scale,
        const float* __restrict__ A, const float* __restrict__ W,
        const float* __restrict__ dinv, float* __restrict__ C, int n) {
    const int BM = 128, BK = 32, COUT = 128, TN = 8;
    __shared__ float sA[BM * BK];
    __shared__ float sW[BK * COUT];

    int t8 = blockIdx.x >> 3, l = blockIdx.x & 7;
    int m = t8 % 3, q = t8 / 3;

    if (m < 2) {
        int g = q * 2 + m;
        if (g < FILL_G)
            fill_role(src, pack, rowptr, csr_src, e, scale, l, g);
        return;
    }

    int bid = q * 8 + l;
    int row0 = bid * BM;
    if (row0 >= n) return;

    int tid = threadIdx.x;
    int lane = tid & 63;
    int wv = tid >> 6;
    int tr = tid & 15, tc = tid >> 4;
    int c0 = tc * TN;

    float acc[8][TN];
#pragma unroll
    for (int i = 0; i < 8; ++i)
#pragma unroll
        for (int j = 0; j < TN; ++j) acc[i][j] = 0.f;

    for (int slab = 0; slab < 4; ++slab) {
        if (slab) __syncthreads();

#pragma unroll
        for (int it = 0; it < 4; ++it) {
            int chunk = it * 4 + wv;
            int L = chunk * 64 + lane;
            int row = L >> 3;
            int gp = L & 7;
            int gsrc = gp ^ ((row >> 3) & 7);
            int grow = min(row0 + row, n - 1);
            const float* srcp = A + (long)grow * 128 + slab * 32 + gsrc * 4;
            float* dstp = sA + chunk * 256;
            __builtin_amdgcn_global_load_lds(
                (const __attribute__((address_space(1))) void*)srcp,
                (__attribute__((address_space(3))) void*)dstp, 16, 0, 0);
        }
#pragma unroll
        for (int it = 0; it < 4; ++it) {
            int chunk = it * 4 + wv;
            int L = chunk * 64 + lane;
            int k = L >> 5;
            int gp = L & 31;
            const float* srcp = W + (long)(slab * 32 + k) * COUT + gp * 4;
            float* dstp = sW + chunk * 256;
            __builtin_amdgcn_global_load_lds(
                (const __attribute__((address_space(1))) void*)srcp,
                (__attribute__((address_space(3))) void*)dstp, 16, 0, 0);
        }
        __syncthreads();

#pragma unroll
        for (int k4 = 0; k4 < 8; ++k4) {
            int slot = k4 ^ (tr & 7);
            float4 a4[8];
#pragma unroll
            for (int i = 0; i < 8; ++i)
                a4[i] = *reinterpret_cast<const float4*>(&sA[(tr * 8 + i) * 32 + slot * 4]);
#pragma unroll
            for (int kk = 0; kk < 4; ++kk) {
                float w[TN];
#pragma unroll
                for (int j = 0; j < TN; j += 4)
                    *reinterpret_cast<float4*>(&w[j]) =
                        *reinterpret_cast<const float4*>(&sW[(k4 * 4 + kk) * COUT + c0 + j]);
#pragma unroll
                for (int i = 0; i < 8; ++i) {
                    float av = (kk == 0) ? a4[i].x : (kk == 1) ? a4[i].y
                             : (kk == 2) ? a4[i].z : a4[i].w;
#pragma unroll
                    for (int j = 0; j < TN; ++j)
                        acc[i][j] = fmaf(av, w[j], acc[i][j]);
                }
            }
        }
    }

#pragma unroll
    for (int i = 0; i < 8; ++i) {
        int row = row0 + tr * 8 + i;
        if (row < n) {
            float dv = dinv[row];
#pragma unroll
            for (int j = 0; j < TN; ++j) acc[i][j] *= dv;
            *reinterpret_cast<float4*>(C + (long)row * COUT + c0) =
                *reinterpret_cast<float4*>(&acc[i][0]);
            *reinterpret_cast<float4*>(C + (long)row * COUT + c0 + 4) =
                *reinterpret_cast<float4*>(&acc[i][4]);
        }
    }
}

// ================= GEMM<64> body (shared by standalone + fused) =================

__device__ __forceinline__ void gemm64_body(const float* __restrict__ A,
                                            const float* __restrict__ W,
                                            const float* __restrict__ dinv,
                                            float* __restrict__ C, int n, int row0) {
    const int BK = 32, COUT = 64, TN = 4;
    __shared__ float sA[128 * BK];            // 16 KB
    __shared__ float sW[BK * COUT];           // 8 KB

    int tid = threadIdx.x;
    int lane = tid & 63;
    int wv = tid >> 6;
    int tr = tid & 15, tc = tid >> 4;
    int c0 = tc * TN;

    float acc[8][TN];
#pragma unroll
    for (int i = 0; i < 8; ++i)
#pragma unroll
        for (int j = 0; j < TN; ++j) acc[i][j] = 0.f;

    for (int slab = 0; slab < 4; ++slab) {
        if (slab) __syncthreads();

#pragma unroll
        for (int it = 0; it < 4; ++it) {
            int chunk = it * 4 + wv;
            int L = chunk * 64 + lane;
            int row = L >> 3;
            int gp = L & 7;
            int gsrc = gp ^ ((row >> 3) & 7);
            int grow = min(row0 + row, n - 1);
            const float* srcp = A + (long)grow * 128 + slab * 32 + gsrc * 4;
            float* dstp = sA + chunk * 256;
            __builtin_amdgcn_global_load_lds(
                (const __attribute__((address_space(1))) void*)srcp,
                (__attribute__((address_space(3))) void*)dstp, 16, 0, 0);
        }
#pragma unroll
        for (int it = 0; it < 2; ++it) {
            int chunk = it * 4 + wv;
            int L = chunk * 64 + lane;
            int k = L >> 4;
            int gp = L & 15;
            const float* srcp = W + (long)(slab * 32 + k) * COUT + gp * 4;
            float* dstp = sW + chunk * 256;
            __builtin_amdgcn_global_load_lds(
                (const __attribute__((address_space(1))) void*)srcp,
                (__attribute__((address_space(3))) void*)dstp, 16, 0, 0);
        }
        __syncthreads();

#pragma unroll
        for (int k4 = 0; k4 < 8; ++k4) {
            int slot = k4 ^ (tr & 7);
            float4 a4[8];
#pragma unroll
            for (int i = 0; i < 8; ++i)
                a4[i] = *reinterpret_cast<const float4*>(&sA[(tr * 8 + i) * 32 + slot * 4]);
#pragma unroll
            for (int kk = 0; kk < 4; ++kk) {
                float w[TN];
                *reinterpret_cast<float4*>(&w[0]) =
                    *reinterpret_cast<const float4*>(&sW[(k4 * 4 + kk) * COUT + c0]);
#pragma unroll
                for (int i = 0; i < 8; ++i) {
                    float av = (kk == 0) ? a4[i].x : (kk == 1) ? a4[i].y
                             : (kk == 2) ? a4[i].z : a4[i].w;
#pragma unroll
                    for (int j = 0; j < TN; ++j)
                        acc[i][j] = fmaf(av, w[j], acc[i][j]);
                }
            }
        }
    }

#pragma unroll
    for (int i = 0; i < 8; ++i) {
        int row = row0 + tr * 8 + i;
        if (row < n) {
            float dv = dinv[row];
#pragma unroll
            for (int j = 0; j < TN; ++j) acc[i][j] *= dv;
            *reinterpret_cast<float4*>(C + (long)row * COUT + c0) =
                *reinterpret_cast<float4*>(&acc[i][0]);
        }
    }
}

__global__ __launch_bounds__(256) void k_gemm64(const float* __restrict__ A,
                                                const float* __restrict__ W,
                                                const float* __restrict__ dinv,
                                                float* __restrict__ C, int n, int rowbase) {
    gemm64_body(A, W, dinv, C, n, rowbase + blockIdx.x * 128);
}

// ================= gather body (shared) =================

template<int C, bool RELU>
__device__ __forceinline__ void gather_node(const int* __restrict__ rowptr,
                                            const int* __restrict__ csr_src,
                                            const float* __restrict__ dinv,
                                            const float* __restrict__ h,
                                            const float* __restrict__ bias,
                                            float* __restrict__ out, int node, int c) {
    const float4* h4 = reinterpret_cast<const float4*>(h);
    float4 acc = h4[((long)node * C + c) >> 2];   // self-loop (already dinv-scaled)

    int beg = rowptr[node], end = rowptr[node + 1];
    int e = beg;
    for (; e + 8 <= end; e += 8) {
        int s[8];
#pragma unroll
        for (int q = 0; q < 8; ++q) s[q] = csr_src[e + q];
        float4 u[8];
#pragma unroll
        for (int q = 0; q < 8; ++q) u[q] = h4[((long)s[q] * C + c) >> 2];
        float sx0 = (u[0].x + u[1].x) + (u[2].x + u[3].x);
        float sx1 = (u[4].x + u[5].x) + (u[6].x + u[7].x);
        float sy0 = (u[0].y + u[1].y) + (u[2].y + u[3].y);
        float sy1 = (u[4].y + u[5].y) + (u[6].y + u[7].y);
        float sz0 = (u[0].z + u[1].z) + (u[2].z + u[3].z);
        float sz1 = (u[4].z + u[5].z) + (u[6].z + u[7].z);
        float sw0 = (u[0].w + u[1].w) + (u[2].w + u[3].w);
        float sw1 = (u[4].w + u[5].w) + (u[6].w + u[7].w);
        acc.x += sx0 + sx1; acc.y += sy0 + sy1;
        acc.z += sz0 + sz1; acc.w += sw0 + sw1;
    }
    for (; e < end; ++e) {
        int s = csr_src[e];
        float4 u = h4[((long)s * C + c) >> 2];
        acc.x += u.x; acc.y += u.y; acc.z += u.z; acc.w += u.w;
    }
    float dd = dinv[node];
    float4 b4 = *reinterpret_cast<const float4*>(bias + c);
    acc.x = fmaf(acc.x, dd, b4.x);
    acc.y = fmaf(acc.y, dd, b4.y);
    acc.z = fmaf(acc.z, dd, b4.z);
    acc.w = fmaf(acc.w, dd, b4.w);
    if (RELU) {
        acc.x = fmaxf(acc.x, 0.f); acc.y = fmaxf(acc.y, 0.f);
        acc.z = fmaxf(acc.z, 0.f); acc.w = fmaxf(acc.w, 0.f);
    }
    *reinterpret_cast<float4*>(out + (long)node * C + c) = acc;
}

template<int C, bool RELU>
__global__ void k_gather(const int* __restrict__ rowptr, const int* __restrict__ csr_src,
                         const float* __restrict__ dinv, const float* __restrict__ h,
                         const float* __restrict__ bias, float* __restrict__ out,
                         int nbeg, int nend) {
    const int TPN = C / 4;
    int t = blockIdx.x * blockDim.x + threadIdx.x;
    int node = nbeg + t / TPN;
    if (node >= nend) return;
    gather_node<C, RELU>(rowptr, csr_src, dinv, h, bias, out, node, (t % TPN) * 4);
}

// ================= FUSED-2: gather128 part B  ||  gemm64 part A =================

__global__ __launch_bounds__(256) void k_fuse2(
        const int* __restrict__ rowptr, const int* __restrict__ csr_src,
        const float* __restrict__ dinv, const float* __restrict__ ht,
        const float* __restrict__ b1, float* __restrict__ h,
        const float* __restrict__ W2, float* __restrict__ z,
        int n, int H1, int NG64) {
    if ((int)blockIdx.x < NG64) {
        gemm64_body(h, W2, dinv, z, n, blockIdx.x * 128);   // rows [0,H1)
        return;
    }
    int g = blockIdx.x - NG64;
    int node = H1 + g * 8 + (threadIdx.x >> 5);
    if (node < n)
        gather_node<128, true>(rowptr, csr_src, dinv, ht, b1, h, node, (threadIdx.x & 31) * 4);
}

// ================= decode =================

__global__ void k_decode(const int* __restrict__ ia, const int* __restrict__ ib,
                         const float* __restrict__ z, float* __restrict__ out, int m) {
    int t = blockIdx.x * blockDim.x + threadIdx.x;
    int k = t / 16;
    if (k >= m) return;
    int c = (t & 15) * 4;
    int a = ia[k], b = ib[k];
    float4 va = *reinterpret_cast<const float4*>(z + (long)a * 64 + c);
    float4 vb = *reinterpret_cast<const float4*>(z + (long)b * 64 + c);
    float dot = va.x * vb.x + va.y * vb.y + va.z * vb.z + va.w * vb.w;
    dot += __shfl_xor(dot, 8);
    dot += __shfl_xor(dot, 4);
    dot += __shfl_xor(dot, 2);
    dot += __shfl_xor(dot, 1);
    if ((t & 15) == 0) out[k] = dot;
}

// ================= launcher =================

extern "C" void kernel_launch(void* const* d_in, const int* in_sizes, int n_in,
                              void* d_out, int out_size, void* d_ws, size_t ws_size,
                              hipStream_t stream) {
    const float* x  = (const float*)d_in[0];
    const int*   ei = (const int*)d_in[1];
    const int*   el = (const int*)d_in[2];
    const float* W1 = (const float*)d_in[3];
    const float* b1 = (const float*)d_in[4];
    const float* W2 = (const float*)d_in[5];
    const float* b2 = (const float*)d_in[6];
    float* out = (float*)d_out;

    const int N = in_sizes[0] / 128;
    const int E = in_sizes[1] / 2;
    const int L = out_size;

    const int* src = ei;
    const int* dst = ei + E;
    const int* la  = el;
    const int* lb  = el + L;

    auto cdiv = [](long a, long b) { return (int)((a + b - 1) / b); };

    // pipelined layout needs: bufA + bufB + z + csr + cnt + rowptr + dinv + part
    size_t need = ((size_t)N * 128 * 2 + (size_t)N * 64) * 4 + (size_t)E * 4
                + ((size_t)N * 3 + 8 + SCP) * 4;
    bool pipelined = (ws_size >= need);

    float* bufA = (float*)d_ws;                     // N*128 h-tilde
    float* bufB = bufA + (long)N * 128;             // N*128 h (pack overlays pre-fuse)
    float* z;
    int*   csr_src;
    if (pipelined) {
        z = bufB + (long)N * 128;                   // N*64 separate
        csr_src = (int*)(z + (long)N * 64);
    } else {
        z = bufA;                                   // serial fallback (R11 layout)
        csr_src = (int*)(bufB + (long)N * 128);
    }
    int*   cnt    = csr_src + E;                    // N
    int*   rowptr = cnt + N;                        // N+1
    float* dinv   = (float*)(rowptr + N + 1);       // N
    int*   part   = (int*)(dinv + N);               // SCP
    unsigned int* pack = (unsigned int*)bufB;       // E u32 (dies at end of k_fuse)
    float* zout = pipelined ? bufA : (bufA + (long)N * 64);  // N*64

    // ---- CSR build + normalization ----
    hipMemsetAsync(cnt, 0, (size_t)N * sizeof(int), stream);
    k_count <<<cdiv(E, 256), 256, 0, stream>>>(dst, cnt, pack, E);
    k_scan_a<<<SCP / 256, 256, 0, stream>>>(cnt, part, N);
    k_scan_b<<<1, SCP, 0, stream>>>(part);
    k_scan_c<<<SCP / 256, 256, 0, stream>>>(cnt, part, rowptr, dinv, N);

    // ---- fused: CSR fill || layer-1 GEMM ----
    k_fuse<<<294 * 8, 256, 0, stream>>>(src, pack, rowptr, csr_src, E, 8.0f / (float)N,
                                        x, W1, dinv, bufA, N);

    if (pipelined) {
        const int H1 = ((N / 2 + 127) / 128) * 128;     // 50048
        const int NG64 = H1 / 128;                      // 391
        const int NB2 = cdiv(N - H1, 8);
        // gather128 part A: h rows [0,H1)
        k_gather<128, true><<<cdiv((long)H1 * 32, 256), 256, 0, stream>>>(
            rowptr, csr_src, dinv, bufA, b1, bufB, 0, H1);
        // fused: gather128 part B || gemm64 part A
        k_fuse2<<<NG64 + NB2, 256, 0, stream>>>(rowptr, csr_src, dinv, bufA, b1, bufB,
                                                W2, z, N, H1, NG64);
        // gemm64 part B: rows [H1,N)
        k_gemm64<<<cdiv(N - H1, 128), 256, 0, stream>>>(bufB, W2, dinv, z, N, H1);
    } else {
        k_gather<128, true><<<cdiv((long)N * 32, 256), 256, 0, stream>>>(
            rowptr, csr_src, dinv, bufA, b1, bufB, 0, N);
        k_gemm64<<<cdiv(N, 128), 256, 0, stream>>>(bufB, W2, dinv, z, N, 0);
    }

    // ---- layer 2 aggregation + decode ----
    k_gather<64, false><<<cdiv((long)N * 16, 256), 256, 0, stream>>>(
        rowptr, csr_src, dinv, z, b2, zout, 0, N);
    k_decode<<<cdiv((long)L * 16, 256), 256, 0, stream>>>(la, lb, zout, out, L);
}

// Round 14
// 451.272 us; speedup vs baseline: 1.4190x; 1.0687x over previous
//
#include <hip/hip_runtime.h>

// ================= degree + packed (dst,rank) =================

__global__ void k_count(const int* __restrict__ dst, int* __restrict__ cnt,
                        unsigned int* __restrict__ pack, int e) {
    int i = blockIdx.x * blockDim.x + threadIdx.x;
    if (i < e) {
        int d = dst[i];
        int r = atomicAdd(&cnt[d], 1);
        pack[i] = ((unsigned int)d << 14) | (unsigned int)r;   // deg < 2^14 guaranteed
    }
}

// ---- 3-phase parallel scan: cnt -> rowptr (+ dinv fused) ----
#define SCP 1024

__global__ void k_scan_a(const int* __restrict__ cnt, int* __restrict__ part, int n) {
    int p = blockIdx.x * blockDim.x + threadIdx.x;
    if (p >= SCP) return;
    int chunk = (n + SCP - 1) / SCP;
    int b = p * chunk, e = min(b + chunk, n), s = 0;
    for (int i = b; i < e; ++i) s += cnt[i];
    part[p] = s;
}

__global__ void k_scan_b(int* __restrict__ part) {   // 1 block, 1024 threads
    __shared__ int sm[SCP];
    int t = threadIdx.x;
    sm[t] = part[t];
    __syncthreads();
    for (int off = 1; off < SCP; off <<= 1) {
        int v = (t >= off) ? sm[t - off] : 0;
        __syncthreads();
        sm[t] += v;
        __syncthreads();
    }
    part[t] = t ? sm[t - 1] : 0;   // exclusive
}

__global__ void k_scan_c(const int* __restrict__ cnt, const int* __restrict__ part,
                         int* __restrict__ rowptr, float* __restrict__ dinv, int n) {
    int p = blockIdx.x * blockDim.x + threadIdx.x;
    if (p >= SCP) return;
    int chunk = (n + SCP - 1) / SCP;
    int b = p * chunk, e = min(b + chunk, n);
    int run = part[p];
    for (int i = b; i < e; ++i) {
        rowptr[i] = run;
        dinv[i] = rsqrtf((float)(cnt[i] + 1));   // +1 self-loop
        run += cnt[i];
    }
    if (p == SCP - 1) rowptr[n] = run;
}

// ================= FUSED: XCD-partitioned CSR fill  ||  GEMM<128> =================
// PLAIN stores for csr_src: writes accumulate in the owning XCD's L2 (region
// 0.8MB/XCD) and flush once. (nt-store bypassed L2 -> 10x write-through cost.)

#define FILL_G 192

__device__ __forceinline__ void fill_role(const int* __restrict__ src,
                                          const unsigned int* __restrict__ pack,
                                          const int* __restrict__ rowptr,
                                          int* __restrict__ csr_src,
                                          int e, float scale, int r, int g) {
    int chunk = (e + FILL_G - 1) / FILL_G;
    int beg = g * chunk, end = min(beg + chunk, e);
    for (int i = beg + threadIdx.x; i < end; i += blockDim.x) {
        unsigned int p = pack[i];
        int d = (int)(p >> 14);
        if ((int)((float)d * scale) == r) {
            int pos = rowptr[d] + (int)(p & 0x3FFFu);
            csr_src[pos] = src[i];
        }
    }
}

__global__ __launch_bounds__(256) void k_fuse(
        const int* __restrict__ src, const unsigned int* __restrict__ pack,
        const int* __restrict__ rowptr, int* __restrict__ csr_src, int e, float scale,
        const float* __restrict__ A, const float* __restrict__ W,
        const float* __restrict__ dinv, float* __restrict__ C, int n) {
    const int BM = 128, BK = 32, COUT = 128, TN = 8;
    __shared__ float sA[BM * BK];
    __shared__ float sW[BK * COUT];

    int t8 = blockIdx.x >> 3, l = blockIdx.x & 7;
    int m = t8 % 3, q = t8 / 3;

    if (m < 2) {
        int g = q * 2 + m;
        if (g < FILL_G)
            fill_role(src, pack, rowptr, csr_src, e, scale, l, g);
        return;
    }

    int bid = q * 8 + l;
    int row0 = bid * BM;
    if (row0 >= n) return;

    int tid = threadIdx.x;
    int lane = tid & 63;
    int wv = tid >> 6;
    int tr = tid & 15, tc = tid >> 4;
    int c0 = tc * TN;

    float acc[8][TN];
#pragma unroll
    for (int i = 0; i < 8; ++i)
#pragma unroll
        for (int j = 0; j < TN; ++j) acc[i][j] = 0.f;

    for (int slab = 0; slab < 4; ++slab) {
        if (slab) __syncthreads();

#pragma unroll
        for (int it = 0; it < 4; ++it) {
            int chunk = it * 4 + wv;
            int L = chunk * 64 + lane;
            int row = L >> 3;
            int gp = L & 7;
            int gsrc = gp ^ ((row >> 3) & 7);
            int grow = min(row0 + row, n - 1);
            const float* srcp = A + (long)grow * 128 + slab * 32 + gsrc * 4;
            float* dstp = sA + chunk * 256;
            __builtin_amdgcn_global_load_lds(
                (const __attribute__((address_space(1))) void*)srcp,
                (__attribute__((address_space(3))) void*)dstp, 16, 0, 0);
        }
#pragma unroll
        for (int it = 0; it < 4; ++it) {
            int chunk = it * 4 + wv;
            int L = chunk * 64 + lane;
            int k = L >> 5;
            int gp = L & 31;
            const float* srcp = W + (long)(slab * 32 + k) * COUT + gp * 4;
            float* dstp = sW + chunk * 256;
            __builtin_amdgcn_global_load_lds(
                (const __attribute__((address_space(1))) void*)srcp,
                (__attribute__((address_space(3))) void*)dstp, 16, 0, 0);
        }
        __syncthreads();

#pragma unroll
        for (int k4 = 0; k4 < 8; ++k4) {
            int slot = k4 ^ (tr & 7);
            float4 a4[8];
#pragma unroll
            for (int i = 0; i < 8; ++i)
                a4[i] = *reinterpret_cast<const float4*>(&sA[(tr * 8 + i) * 32 + slot * 4]);
#pragma unroll
            for (int kk = 0; kk < 4; ++kk) {
                float w[TN];
#pragma unroll
                for (int j = 0; j < TN; j += 4)
                    *reinterpret_cast<float4*>(&w[j]) =
                        *reinterpret_cast<const float4*>(&sW[(k4 * 4 + kk) * COUT + c0 + j]);
#pragma unroll
                for (int i = 0; i < 8; ++i) {
                    float av = (kk == 0) ? a4[i].x : (kk == 1) ? a4[i].y
                             : (kk == 2) ? a4[i].z : a4[i].w;
#pragma unroll
                    for (int j = 0; j < TN; ++j)
                        acc[i][j] = fmaf(av, w[j], acc[i][j]);
                }
            }
        }
    }

#pragma unroll
    for (int i = 0; i < 8; ++i) {
        int row = row0 + tr * 8 + i;
        if (row < n) {
            float dv = dinv[row];
#pragma unroll
            for (int j = 0; j < TN; ++j) acc[i][j] *= dv;
            *reinterpret_cast<float4*>(C + (long)row * COUT + c0) =
                *reinterpret_cast<float4*>(&acc[i][0]);
            *reinterpret_cast<float4*>(C + (long)row * COUT + c0 + 4) =
                *reinterpret_cast<float4*>(&acc[i][4]);
        }
    }
}

// ================= GEMM<64>: C[row] = dinv[row] * (A[row] @ W) =================

__global__ __launch_bounds__(256) void k_gemm64(const float* __restrict__ A,
                                                const float* __restrict__ W,
                                                const float* __restrict__ dinv,
                                                float* __restrict__ C, int n) {
    const int BK = 32, COUT = 64, TN = 4;
    __shared__ float sA[128 * BK];            // 16 KB
    __shared__ float sW[BK * COUT];           // 8 KB

    int tid = threadIdx.x;
    int lane = tid & 63;
    int wv = tid >> 6;
    int row0 = blockIdx.x * 128;
    int tr = tid & 15, tc = tid >> 4;
    int c0 = tc * TN;

    float acc[8][TN];
#pragma unroll
    for (int i = 0; i < 8; ++i)
#pragma unroll
        for (int j = 0; j < TN; ++j) acc[i][j] = 0.f;

    for (int slab = 0; slab < 4; ++slab) {
        if (slab) __syncthreads();

#pragma unroll
        for (int it = 0; it < 4; ++it) {
            int chunk = it * 4 + wv;
            int L = chunk * 64 + lane;
            int row = L >> 3;
            int gp = L & 7;
            int gsrc = gp ^ ((row >> 3) & 7);
            int grow = min(row0 + row, n - 1);
            const float* srcp = A + (long)grow * 128 + slab * 32 + gsrc * 4;
            float* dstp = sA + chunk * 256;
            __builtin_amdgcn_global_load_lds(
                (const __attribute__((address_space(1))) void*)srcp,
                (__attribute__((address_space(3))) void*)dstp, 16, 0, 0);
        }
#pragma unroll
        for (int it = 0; it < 2; ++it) {
            int chunk = it * 4 + wv;
            int L = chunk * 64 + lane;
            int k = L >> 4;
            int gp = L & 15;
            const float* srcp = W + (long)(slab * 32 + k) * COUT + gp * 4;
            float* dstp = sW + chunk * 256;
            __builtin_amdgcn_global_load_lds(
                (const __attribute__((address_space(1))) void*)srcp,
                (__attribute__((address_space(3))) void*)dstp, 16, 0, 0);
        }
        __syncthreads();

#pragma unroll
        for (int k4 = 0; k4 < 8; ++k4) {
            int slot = k4 ^ (tr & 7);
            float4 a4[8];
#pragma unroll
            for (int i = 0; i < 8; ++i)
                a4[i] = *reinterpret_cast<const float4*>(&sA[(tr * 8 + i) * 32 + slot * 4]);
#pragma unroll
            for (int kk = 0; kk < 4; ++kk) {
                float w[TN];
                *reinterpret_cast<float4*>(&w[0]) =
                    *reinterpret_cast<const float4*>(&sW[(k4 * 4 + kk) * COUT + c0]);
#pragma unroll
                for (int i = 0; i < 8; ++i) {
                    float av = (kk == 0) ? a4[i].x : (kk == 1) ? a4[i].y
                             : (kk == 2) ? a4[i].z : a4[i].w;
#pragma unroll
                    for (int j = 0; j < TN; ++j)
                        acc[i][j] = fmaf(av, w[j], acc[i][j]);
                }
            }
        }
    }

#pragma unroll
    for (int i = 0; i < 8; ++i) {
        int row = row0 + tr * 8 + i;
        if (row < n) {
            float dv = dinv[row];
#pragma unroll
            for (int j = 0; j < TN; ++j) acc[i][j] *= dv;
            *reinterpret_cast<float4*>(C + (long)row * COUT + c0) =
                *reinterpret_cast<float4*>(&acc[i][0]);
        }
    }
}

// ================= pull aggregation (row-major, 8-deep MLP) =================

template<int C, bool RELU>
__global__ void k_gather(const int* __restrict__ rowptr, const int* __restrict__ csr_src,
                         const float* __restrict__ dinv, const float* __restrict__ h,
                         const float* __restrict__ bias, float* __restrict__ out, int n) {
    const int TPN = C / 4;
    int t = blockIdx.x * blockDim.x + threadIdx.x;
    int node = t / TPN;
    if (node >= n) return;
    int c = (t % TPN) * 4;

    const float4* h4 = reinterpret_cast<const float4*>(h);
    float4 acc = h4[((long)node * C + c) >> 2];   // self-loop term (already dinv-scaled)

    int beg = rowptr[node], end = rowptr[node + 1];
    int e = beg;
    for (; e + 8 <= end; e += 8) {
        int s[8];
#pragma unroll
        for (int q = 0; q < 8; ++q) s[q] = csr_src[e + q];
        float4 u[8];
#pragma unroll
        for (int q = 0; q < 8; ++q) u[q] = h4[((long)s[q] * C + c) >> 2];
        float sx0 = (u[0].x + u[1].x) + (u[2].x + u[3].x);
        float sx1 = (u[4].x + u[5].x) + (u[6].x + u[7].x);
        float sy0 = (u[0].y + u[1].y) + (u[2].y + u[3].y);
        float sy1 = (u[4].y + u[5].y) + (u[6].y + u[7].y);
        float sz0 = (u[0].z + u[1].z) + (u[2].z + u[3].z);
        float sz1 = (u[4].z + u[5].z) + (u[6].z + u[7].z);
        float sw0 = (u[0].w + u[1].w) + (u[2].w + u[3].w);
        float sw1 = (u[4].w + u[5].w) + (u[6].w + u[7].w);
        acc.x += sx0 + sx1; acc.y += sy0 + sy1;
        acc.z += sz0 + sz1; acc.w += sw0 + sw1;
    }
    for (; e < end; ++e) {
        int s = csr_src[e];
        float4 u = h4[((long)s * C + c) >> 2];
        acc.x += u.x; acc.y += u.y; acc.z += u.z; acc.w += u.w;
    }
    float dd = dinv[node];
    float4 b4 = *reinterpret_cast<const float4*>(bias + c);
    acc.x = fmaf(acc.x, dd, b4.x);
    acc.y = fmaf(acc.y, dd, b4.y);
    acc.z = fmaf(acc.z, dd, b4.z);
    acc.w = fmaf(acc.w, dd, b4.w);
    if (RELU) {
        acc.x = fmaxf(acc.x, 0.f); acc.y = fmaxf(acc.y, 0.f);
        acc.z = fmaxf(acc.z, 0.f); acc.w = fmaxf(acc.w, 0.f);
    }
    reinterpret_cast<float4*>(out)[((long)node * C + c) >> 2] = acc;
}

// ================= decode =================

__global__ void k_decode(const int* __restrict__ ia, const int* __restrict__ ib,
                         const float* __restrict__ z, float* __restrict__ out, int m) {
    int t = blockIdx.x * blockDim.x + threadIdx.x;
    int k = t / 16;
    if (k >= m) return;
    int c = (t & 15) * 4;
    int a = ia[k], b = ib[k];
    float4 va = *reinterpret_cast<const float4*>(z + (long)a * 64 + c);
    float4 vb = *reinterpret_cast<const float4*>(z + (long)b * 64 + c);
    float dot = va.x * vb.x + va.y * vb.y + va.z * vb.z + va.w * vb.w;
    dot += __shfl_xor(dot, 8);
    dot += __shfl_xor(dot, 4);
    dot += __shfl_xor(dot, 2);
    dot += __shfl_xor(dot, 1);
    if ((t & 15) == 0) out[k] = dot;
}

// ================= launcher =================

extern "C" void kernel_launch(void* const* d_in, const int* in_sizes, int n_in,
                              void* d_out, int out_size, void* d_ws, size_t ws_size,
                              hipStream_t stream) {
    const float* x  = (const float*)d_in[0];
    const int*   ei = (const int*)d_in[1];
    const int*   el = (const int*)d_in[2];
    const float* W1 = (const float*)d_in[3];
    const float* b1 = (const float*)d_in[4];
    const float* W2 = (const float*)d_in[5];
    const float* b2 = (const float*)d_in[6];
    float* out = (float*)d_out;

    const int N = in_sizes[0] / 128;
    const int E = in_sizes[1] / 2;
    const int L = out_size;

    const int* src = ei;
    const int* dst = ei + E;
    const int* la  = el;
    const int* lb  = el + L;

    // ---- workspace layout (R11 serial layout) ----
    float* bufA = (float*)d_ws;                     // N*128 h-tilde
    float* bufB = bufA + (long)N * 128;             // N*128 (pack overlays; later h row-major)
    int*   csr_src = (int*)(bufB + (long)N * 128);  // E
    int*   cnt     = csr_src + E;                   // N
    int*   rowptr  = cnt + N;                       // N+1
    float* dinv    = (float*)(rowptr + N + 1);      // N
    int*   part    = (int*)(dinv + N);              // SCP
    unsigned int* pack = (unsigned int*)bufB;       // E u32 (dies at end of k_fuse)
    float* z    = bufA;                             // N*64 (reuse)
    float* zout = bufA + (long)N * 64;              // N*64

    auto cdiv = [](long a, long b) { return (int)((a + b - 1) / b); };

    // ---- CSR build + normalization ----
    hipMemsetAsync(cnt, 0, (size_t)N * sizeof(int), stream);
    k_count <<<cdiv(E, 256), 256, 0, stream>>>(dst, cnt, pack, E);
    k_scan_a<<<SCP / 256, 256, 0, stream>>>(cnt, part, N);
    k_scan_b<<<1, SCP, 0, stream>>>(part);
    k_scan_c<<<SCP / 256, 256, 0, stream>>>(cnt, part, rowptr, dinv, N);

    // ---- fused: CSR fill || layer-1 GEMM ----
    k_fuse<<<294 * 8, 256, 0, stream>>>(src, pack, rowptr, csr_src, E, 8.0f / (float)N,
                                        x, W1, dinv, bufA, N);

    // ---- layer 1 aggregation: h = relu(agg) + b1 ----
    k_gather<128, true><<<cdiv((long)N * 32, 256), 256, 0, stream>>>(
        rowptr, csr_src, dinv, bufA, b1, bufB, N);

    // ---- layer 2: z = agg(h @ W2) + b2 ----
    k_gemm64<<<cdiv(N, 128), 256, 0, stream>>>(bufB, W2, dinv, z, N);
    k_gather<64, false><<<cdiv((long)N * 16, 256), 256, 0, stream>>>(
        rowptr, csr_src, dinv, z, b2, zout, N);

    // ---- decode ----
    k_decode<<<cdiv((long)L * 16, 256), 256, 0, stream>>>(la, lb, zout, out, L);
}

// Round 15
// 398.891 us; speedup vs baseline: 1.6053x; 1.1313x over previous
//
#include <hip/hip_runtime.h>

// ---- bf16 helpers (RNE pack, exact unpack) ----
__device__ __forceinline__ unsigned int f2bf(float f) {
    unsigned int u = __float_as_uint(f);
    return (u + 0x7FFFu + ((u >> 16) & 1u)) >> 16;
}
__device__ __forceinline__ float bf_lo(unsigned int w) { return __uint_as_float(w << 16); }
__device__ __forceinline__ float bf_hi(unsigned int w) { return __uint_as_float(w & 0xffff0000u); }

// ================= degree + packed (dst,rank) =================

__global__ void k_count(const int* __restrict__ dst, int* __restrict__ cnt,
                        unsigned int* __restrict__ pack, int e) {
    int i = blockIdx.x * blockDim.x + threadIdx.x;
    if (i < e) {
        int d = dst[i];
        int r = atomicAdd(&cnt[d], 1);
        pack[i] = ((unsigned int)d << 14) | (unsigned int)r;   // deg < 2^14 guaranteed
    }
}

// ---- 3-phase parallel scan: cnt -> rowptr (+ dinv fused) ----
#define SCP 1024

__global__ void k_scan_a(const int* __restrict__ cnt, int* __restrict__ part, int n) {
    int p = blockIdx.x * blockDim.x + threadIdx.x;
    if (p >= SCP) return;
    int chunk = (n + SCP - 1) / SCP;
    int b = p * chunk, e = min(b + chunk, n), s = 0;
    for (int i = b; i < e; ++i) s += cnt[i];
    part[p] = s;
}

__global__ void k_scan_b(int* __restrict__ part) {   // 1 block, 1024 threads
    __shared__ int sm[SCP];
    int t = threadIdx.x;
    sm[t] = part[t];
    __syncthreads();
    for (int off = 1; off < SCP; off <<= 1) {
        int v = (t >= off) ? sm[t - off] : 0;
        __syncthreads();
        sm[t] += v;
        __syncthreads();
    }
    part[t] = t ? sm[t - 1] : 0;   // exclusive
}

__global__ void k_scan_c(const int* __restrict__ cnt, const int* __restrict__ part,
                         int* __restrict__ rowptr, float* __restrict__ dinv, int n) {
    int p = blockIdx.x * blockDim.x + threadIdx.x;
    if (p >= SCP) return;
    int chunk = (n + SCP - 1) / SCP;
    int b = p * chunk, e = min(b + chunk, n);
    int run = part[p];
    for (int i = b; i < e; ++i) {
        rowptr[i] = run;
        dinv[i] = rsqrtf((float)(cnt[i] + 1));   // +1 self-loop
        run += cnt[i];
    }
    if (p == SCP - 1) rowptr[n] = run;
}

// ================= FUSED: XCD-partitioned CSR fill  ||  GEMM<128> (bf16 out) =================

#define FILL_G 192

__device__ __forceinline__ void fill_role(const int* __restrict__ src,
                                          const unsigned int* __restrict__ pack,
                                          const int* __restrict__ rowptr,
                                          int* __restrict__ csr_src,
                                          int e, float scale, int r, int g) {
    int chunk = (e + FILL_G - 1) / FILL_G;
    int beg = g * chunk, end = min(beg + chunk, e);
    for (int i = beg + threadIdx.x; i < end; i += blockDim.x) {
        unsigned int p = pack[i];
        int d = (int)(p >> 14);
        if ((int)((float)d * scale) == r) {
            int pos = rowptr[d] + (int)(p & 0x3FFFu);
            csr_src[pos] = src[i];
        }
    }
}

__global__ __launch_bounds__(256) void k_fuse(
        const int* __restrict__ src, const unsigned int* __restrict__ pack,
        const int* __restrict__ rowptr, int* __restrict__ csr_src, int e, float scale,
        const float* __restrict__ A, const float* __restrict__ W,
        const float* __restrict__ dinv, unsigned short* __restrict__ C16, int n) {
    const int BM = 128, BK = 32, COUT = 128, TN = 8;
    __shared__ float sA[BM * BK];
    __shared__ float sW[BK * COUT];

    int t8 = blockIdx.x >> 3, l = blockIdx.x & 7;
    int m = t8 % 3, q = t8 / 3;

    if (m < 2) {
        int g = q * 2 + m;
        if (g < FILL_G)
            fill_role(src, pack, rowptr, csr_src, e, scale, l, g);
        return;
    }

    int bid = q * 8 + l;
    int row0 = bid * BM;
    if (row0 >= n) return;

    int tid = threadIdx.x;
    int lane = tid & 63;
    int wv = tid >> 6;
    int tr = tid & 15, tc = tid >> 4;
    int c0 = tc * TN;

    float acc[8][TN];
#pragma unroll
    for (int i = 0; i < 8; ++i)
#pragma unroll
        for (int j = 0; j < TN; ++j) acc[i][j] = 0.f;

    for (int slab = 0; slab < 4; ++slab) {
        if (slab) __syncthreads();

#pragma unroll
        for (int it = 0; it < 4; ++it) {
            int chunk = it * 4 + wv;
            int L = chunk * 64 + lane;
            int row = L >> 3;
            int gp = L & 7;
            int gsrc = gp ^ ((row >> 3) & 7);
            int grow = min(row0 + row, n - 1);
            const float* srcp = A + (long)grow * 128 + slab * 32 + gsrc * 4;
            float* dstp = sA + chunk * 256;
            __builtin_amdgcn_global_load_lds(
                (const __attribute__((address_space(1))) void*)srcp,
                (__attribute__((address_space(3))) void*)dstp, 16, 0, 0);
        }
#pragma unroll
        for (int it = 0; it < 4; ++it) {
            int chunk = it * 4 + wv;
            int L = chunk * 64 + lane;
            int k = L >> 5;
            int gp = L & 31;
            const float* srcp = W + (long)(slab * 32 + k) * COUT + gp * 4;
            float* dstp = sW + chunk * 256;
            __builtin_amdgcn_global_load_lds(
                (const __attribute__((address_space(1))) void*)srcp,
                (__attribute__((address_space(3))) void*)dstp, 16, 0, 0);
        }
        __syncthreads();

#pragma unroll
        for (int k4 = 0; k4 < 8; ++k4) {
            int slot = k4 ^ (tr & 7);
            float4 a4[8];
#pragma unroll
            for (int i = 0; i < 8; ++i)
                a4[i] = *reinterpret_cast<const float4*>(&sA[(tr * 8 + i) * 32 + slot * 4]);
#pragma unroll
            for (int kk = 0; kk < 4; ++kk) {
                float w[TN];
#pragma unroll
                for (int j = 0; j < TN; j += 4)
                    *reinterpret_cast<float4*>(&w[j]) =
                        *reinterpret_cast<const float4*>(&sW[(k4 * 4 + kk) * COUT + c0 + j]);
#pragma unroll
                for (int i = 0; i < 8; ++i) {
                    float av = (kk == 0) ? a4[i].x : (kk == 1) ? a4[i].y
                             : (kk == 2) ? a4[i].z : a4[i].w;
#pragma unroll
                    for (int j = 0; j < TN; ++j)
                        acc[i][j] = fmaf(av, w[j], acc[i][j]);
                }
            }
        }
    }

    // ---- epilogue: dinv scale + bf16 store ----
#pragma unroll
    for (int i = 0; i < 8; ++i) {
        int row = row0 + tr * 8 + i;
        if (row < n) {
            float dv = dinv[row];
            uint4 o;
            o.x = f2bf(acc[i][0] * dv) | (f2bf(acc[i][1] * dv) << 16);
            o.y = f2bf(acc[i][2] * dv) | (f2bf(acc[i][3] * dv) << 16);
            o.z = f2bf(acc[i][4] * dv) | (f2bf(acc[i][5] * dv) << 16);
            o.w = f2bf(acc[i][6] * dv) | (f2bf(acc[i][7] * dv) << 16);
            *reinterpret_cast<uint4*>(C16 + (long)row * 128 + c0) = o;
        }
    }
}

// ================= GEMM<64>: bf16 out =================

__global__ __launch_bounds__(256) void k_gemm64(const float* __restrict__ A,
                                                const float* __restrict__ W,
                                                const float* __restrict__ dinv,
                                                unsigned short* __restrict__ C16, int n) {
    const int BK = 32, COUT = 64, TN = 4;
    __shared__ float sA[128 * BK];            // 16 KB
    __shared__ float sW[BK * COUT];           // 8 KB

    int tid = threadIdx.x;
    int lane = tid & 63;
    int wv = tid >> 6;
    int row0 = blockIdx.x * 128;
    int tr = tid & 15, tc = tid >> 4;
    int c0 = tc * TN;

    float acc[8][TN];
#pragma unroll
    for (int i = 0; i < 8; ++i)
#pragma unroll
        for (int j = 0; j < TN; ++j) acc[i][j] = 0.f;

    for (int slab = 0; slab < 4; ++slab) {
        if (slab) __syncthreads();

#pragma unroll
        for (int it = 0; it < 4; ++it) {
            int chunk = it * 4 + wv;
            int L = chunk * 64 + lane;
            int row = L >> 3;
            int gp = L & 7;
            int gsrc = gp ^ ((row >> 3) & 7);
            int grow = min(row0 + row, n - 1);
            const float* srcp = A + (long)grow * 128 + slab * 32 + gsrc * 4;
            float* dstp = sA + chunk * 256;
            __builtin_amdgcn_global_load_lds(
                (const __attribute__((address_space(1))) void*)srcp,
                (__attribute__((address_space(3))) void*)dstp, 16, 0, 0);
        }
#pragma unroll
        for (int it = 0; it < 2; ++it) {
            int chunk = it * 4 + wv;
            int L = chunk * 64 + lane;
            int k = L >> 4;
            int gp = L & 15;
            const float* srcp = W + (long)(slab * 32 + k) * COUT + gp * 4;
            float* dstp = sW + chunk * 256;
            __builtin_amdgcn_global_load_lds(
                (const __attribute__((address_space(1))) void*)srcp,
                (__attribute__((address_space(3))) void*)dstp, 16, 0, 0);
        }
        __syncthreads();

#pragma unroll
        for (int k4 = 0; k4 < 8; ++k4) {
            int slot = k4 ^ (tr & 7);
            float4 a4[8];
#pragma unroll
            for (int i = 0; i < 8; ++i)
                a4[i] = *reinterpret_cast<const float4*>(&sA[(tr * 8 + i) * 32 + slot * 4]);
#pragma unroll
            for (int kk = 0; kk < 4; ++kk) {
                float w[TN];
                *reinterpret_cast<float4*>(&w[0]) =
                    *reinterpret_cast<const float4*>(&sW[(k4 * 4 + kk) * COUT + c0]);
#pragma unroll
                for (int i = 0; i < 8; ++i) {
                    float av = (kk == 0) ? a4[i].x : (kk == 1) ? a4[i].y
                             : (kk == 2) ? a4[i].z : a4[i].w;
#pragma unroll
                    for (int j = 0; j < TN; ++j)
                        acc[i][j] = fmaf(av, w[j], acc[i][j]);
                }
            }
        }
    }

#pragma unroll
    for (int i = 0; i < 8; ++i) {
        int row = row0 + tr * 8 + i;
        if (row < n) {
            float dv = dinv[row];
            uint2 o;
            o.x = f2bf(acc[i][0] * dv) | (f2bf(acc[i][1] * dv) << 16);
            o.y = f2bf(acc[i][2] * dv) | (f2bf(acc[i][3] * dv) << 16);
            *reinterpret_cast<uint2*>(C16 + (long)row * 64 + c0) = o;
        }
    }
}

// ================= pull aggregation from bf16 rows (fp32 accumulate/output) =================
// TPN = C/8 threads/node; each thread one uint4 (8 bf16 channels).

template<int C, bool RELU>
__global__ void k_gather16(const int* __restrict__ rowptr, const int* __restrict__ csr_src,
                           const float* __restrict__ dinv, const unsigned short* __restrict__ h16,
                           const float* __restrict__ bias, float* __restrict__ out, int n) {
    const int TPN = C / 8;
    const int RS = C / 8;                      // row stride in uint4
    int t = blockIdx.x * blockDim.x + threadIdx.x;
    int node = t / TPN;
    if (node >= n) return;
    int cg = t % TPN;

    const uint4* h4 = reinterpret_cast<const uint4*>(h16);
    float acc[8];
    {
        uint4 u = h4[(long)node * RS + cg];    // self-loop (already dinv-scaled)
        acc[0] = bf_lo(u.x); acc[1] = bf_hi(u.x);
        acc[2] = bf_lo(u.y); acc[3] = bf_hi(u.y);
        acc[4] = bf_lo(u.z); acc[5] = bf_hi(u.z);
        acc[6] = bf_lo(u.w); acc[7] = bf_hi(u.w);
    }

    int beg = rowptr[node], end = rowptr[node + 1];
    int e = beg;
    for (; e + 8 <= end; e += 8) {
        int s[8];
#pragma unroll
        for (int q = 0; q < 8; ++q) s[q] = csr_src[e + q];
        uint4 u[8];
#pragma unroll
        for (int q = 0; q < 8; ++q) u[q] = h4[(long)s[q] * RS + cg];
#pragma unroll
        for (int q = 0; q < 8; ++q) {
            acc[0] += bf_lo(u[q].x); acc[1] += bf_hi(u[q].x);
            acc[2] += bf_lo(u[q].y); acc[3] += bf_hi(u[q].y);
            acc[4] += bf_lo(u[q].z); acc[5] += bf_hi(u[q].z);
            acc[6] += bf_lo(u[q].w); acc[7] += bf_hi(u[q].w);
        }
    }
    for (; e < end; ++e) {
        uint4 u = h4[(long)csr_src[e] * RS + cg];
        acc[0] += bf_lo(u.x); acc[1] += bf_hi(u.x);
        acc[2] += bf_lo(u.y); acc[3] += bf_hi(u.y);
        acc[4] += bf_lo(u.z); acc[5] += bf_hi(u.z);
        acc[6] += bf_lo(u.w); acc[7] += bf_hi(u.w);
    }

    float dd = dinv[node];
    int c0 = cg * 8;
    float4 ba = *reinterpret_cast<const float4*>(bias + c0);
    float4 bb = *reinterpret_cast<const float4*>(bias + c0 + 4);
    float4 o1, o2;
    o1.x = fmaf(acc[0], dd, ba.x); o1.y = fmaf(acc[1], dd, ba.y);
    o1.z = fmaf(acc[2], dd, ba.z); o1.w = fmaf(acc[3], dd, ba.w);
    o2.x = fmaf(acc[4], dd, bb.x); o2.y = fmaf(acc[5], dd, bb.y);
    o2.z = fmaf(acc[6], dd, bb.z); o2.w = fmaf(acc[7], dd, bb.w);
    if (RELU) {
        o1.x = fmaxf(o1.x, 0.f); o1.y = fmaxf(o1.y, 0.f);
        o1.z = fmaxf(o1.z, 0.f); o1.w = fmaxf(o1.w, 0.f);
        o2.x = fmaxf(o2.x, 0.f); o2.y = fmaxf(o2.y, 0.f);
        o2.z = fmaxf(o2.z, 0.f); o2.w = fmaxf(o2.w, 0.f);
    }
    *reinterpret_cast<float4*>(out + (long)node * C + c0) = o1;
    *reinterpret_cast<float4*>(out + (long)node * C + c0 + 4) = o2;
}

// ================= decode (fp32 z) =================

__global__ void k_decode(const int* __restrict__ ia, const int* __restrict__ ib,
                         const float* __restrict__ z, float* __restrict__ out, int m) {
    int t = blockIdx.x * blockDim.x + threadIdx.x;
    int k = t / 16;
    if (k >= m) return;
    int c = (t & 15) * 4;
    int a = ia[k], b = ib[k];
    float4 va = *reinterpret_cast<const float4*>(z + (long)a * 64 + c);
    float4 vb = *reinterpret_cast<const float4*>(z + (long)b * 64 + c);
    float dot = va.x * vb.x + va.y * vb.y + va.z * vb.z + va.w * vb.w;
    dot += __shfl_xor(dot, 8);
    dot += __shfl_xor(dot, 4);
    dot += __shfl_xor(dot, 2);
    dot += __shfl_xor(dot, 1);
    if ((t & 15) == 0) out[k] = dot;
}

// ================= launcher =================

extern "C" void kernel_launch(void* const* d_in, const int* in_sizes, int n_in,
                              void* d_out, int out_size, void* d_ws, size_t ws_size,
                              hipStream_t stream) {
    const float* x  = (const float*)d_in[0];
    const int*   ei = (const int*)d_in[1];
    const int*   el = (const int*)d_in[2];
    const float* W1 = (const float*)d_in[3];
    const float* b1 = (const float*)d_in[4];
    const float* W2 = (const float*)d_in[5];
    const float* b2 = (const float*)d_in[6];
    float* out = (float*)d_out;

    const int N = in_sizes[0] / 128;
    const int E = in_sizes[1] / 2;
    const int L = out_size;

    const int* src = ei;
    const int* dst = ei + E;
    const int* la  = el;
    const int* lb  = el + L;

    // ---- workspace layout ----
    float* bufA = (float*)d_ws;                     // region A: N*128 f32 worth of bytes
    float* bufB = bufA + (long)N * 128;             // region B: N*128 f32
    int*   csr_src = (int*)(bufB + (long)N * 128);  // E
    int*   cnt     = csr_src + E;                   // N
    int*   rowptr  = cnt + N;                       // N+1
    float* dinv    = (float*)(rowptr + N + 1);      // N
    int*   part    = (int*)(dinv + N);              // SCP
    unsigned int*   pack = (unsigned int*)bufB;     // E u32   (dies at end of k_fuse)
    unsigned short* ht16 = (unsigned short*)bufA;   // N*128 bf16 (k_fuse out; dies after gather128)
    float*          h32  = bufB;                    // N*128 f32  (gather128 out)
    unsigned short* zt16 = (unsigned short*)bufA;   // N*64 bf16  (gemm64 out; overlays dead ht16)
    float*          zout = bufA + (long)N * 32;     // N*64 f32   (after zt16's 12.8MB)

    auto cdiv = [](long a, long b) { return (int)((a + b - 1) / b); };

    // ---- CSR build + normalization ----
    hipMemsetAsync(cnt, 0, (size_t)N * sizeof(int), stream);
    k_count <<<cdiv(E, 256), 256, 0, stream>>>(dst, cnt, pack, E);
    k_scan_a<<<SCP / 256, 256, 0, stream>>>(cnt, part, N);
    k_scan_b<<<1, SCP, 0, stream>>>(part);
    k_scan_c<<<SCP / 256, 256, 0, stream>>>(cnt, part, rowptr, dinv, N);

    // ---- fused: CSR fill || layer-1 GEMM (bf16 h-tilde out) ----
    k_fuse<<<294 * 8, 256, 0, stream>>>(src, pack, rowptr, csr_src, E, 8.0f / (float)N,
                                        x, W1, dinv, ht16, N);

    // ---- layer 1 aggregation: h = relu(agg) + b1 (fp32 out) ----
    k_gather16<128, true><<<cdiv((long)N * 16, 256), 256, 0, stream>>>(
        rowptr, csr_src, dinv, ht16, b1, h32, N);

    // ---- layer 2: z-tilde = dinv*(h @ W2) (bf16 out), then aggregate ----
    k_gemm64<<<cdiv(N, 128), 256, 0, stream>>>(h32, W2, dinv, zt16, N);
    k_gather16<64, false><<<cdiv((long)N * 8, 256), 256, 0, stream>>>(
        rowptr, csr_src, dinv, zt16, b2, zout, N);

    // ---- decode ----
    k_decode<<<cdiv((long)L * 16, 256), 256, 0, stream>>>(la, lb, zout, out, L);
}

// Round 16
// 328.524 us; speedup vs baseline: 1.9491x; 1.2142x over previous
//
#include <hip/hip_runtime.h>

typedef __attribute__((ext_vector_type(8))) short bfrag8;   // 8 bf16 (4 VGPRs)
typedef __attribute__((ext_vector_type(4))) float facc4;    // MFMA accumulator

__device__ __forceinline__ unsigned int f2bf(float f) {
    unsigned int u = __float_as_uint(f);
    return (u + 0x7FFFu + ((u >> 16) & 1u)) >> 16;
}
__device__ __forceinline__ float bf_lo(unsigned int w) { return __uint_as_float(w << 16); }
__device__ __forceinline__ float bf_hi(unsigned int w) { return __uint_as_float(w & 0xffff0000u); }

// ================= degree + packed (dst,rank) =================

__global__ void k_count(const int* __restrict__ dst, int* __restrict__ cnt,
                        unsigned int* __restrict__ pack, int e) {
    int i = blockIdx.x * blockDim.x + threadIdx.x;
    if (i < e) {
        int d = dst[i];
        int r = atomicAdd(&cnt[d], 1);
        pack[i] = ((unsigned int)d << 14) | (unsigned int)r;   // deg < 2^14
    }
}

// ================= cvt: x -> bf16, W1/W2 -> transposed bf16 =================

__global__ void k_cvt(const float* __restrict__ x, const float* __restrict__ W1,
                      const float* __restrict__ W2, unsigned short* __restrict__ x16,
                      unsigned short* __restrict__ w1t, unsigned short* __restrict__ w2t,
                      int nx8) {
    int t = blockIdx.x * blockDim.x + threadIdx.x;
    if (t < nx8) {
        const float4* xp = reinterpret_cast<const float4*>(x) + (long)t * 2;
        float4 a = xp[0], b = xp[1];
        uint4 o;
        o.x = f2bf(a.x) | (f2bf(a.y) << 16);
        o.y = f2bf(a.z) | (f2bf(a.w) << 16);
        o.z = f2bf(b.x) | (f2bf(b.y) << 16);
        o.w = f2bf(b.z) | (f2bf(b.w) << 16);
        reinterpret_cast<uint4*>(x16)[t] = o;
    } else {
        int u = t - nx8;
        if (u < 128 * 128) {
            int k = u >> 7, nn = u & 127;
            w1t[nn * 128 + k] = (unsigned short)f2bf(W1[u]);
        } else if ((u -= 128 * 128) < 128 * 64) {
            int k = u >> 6, nn = u & 63;
            w2t[nn * 128 + k] = (unsigned short)f2bf(W2[u]);
        }
    }
}

// ---- 3-phase parallel scan: cnt -> rowptr (+ dinv fused) ----
#define SCP 1024

__global__ void k_scan_a(const int* __restrict__ cnt, int* __restrict__ part, int n) {
    int p = blockIdx.x * blockDim.x + threadIdx.x;
    if (p >= SCP) return;
    int chunk = (n + SCP - 1) / SCP;
    int b = p * chunk, e = min(b + chunk, n), s = 0;
    for (int i = b; i < e; ++i) s += cnt[i];
    part[p] = s;
}

__global__ void k_scan_b(int* __restrict__ part) {
    __shared__ int sm[SCP];
    int t = threadIdx.x;
    sm[t] = part[t];
    __syncthreads();
    for (int off = 1; off < SCP; off <<= 1) {
        int v = (t >= off) ? sm[t - off] : 0;
        __syncthreads();
        sm[t] += v;
        __syncthreads();
    }
    part[t] = t ? sm[t - 1] : 0;
}

__global__ void k_scan_c(const int* __restrict__ cnt, const int* __restrict__ part,
                         int* __restrict__ rowptr, float* __restrict__ dinv, int n) {
    int p = blockIdx.x * blockDim.x + threadIdx.x;
    if (p >= SCP) return;
    int chunk = (n + SCP - 1) / SCP;
    int b = p * chunk, e = min(b + chunk, n);
    int run = part[p];
    for (int i = b; i < e; ++i) {
        rowptr[i] = run;
        dinv[i] = rsqrtf((float)(cnt[i] + 1));
        run += cnt[i];
    }
    if (p == SCP - 1) rowptr[n] = run;
}

// ================= FUSED: XCD-partitioned CSR fill || MFMA GEMM<128> =================

#define FILL_G 192

__device__ __forceinline__ void fill_role(const int* __restrict__ src,
                                          const unsigned int* __restrict__ pack,
                                          const int* __restrict__ rowptr,
                                          int* __restrict__ csr_src,
                                          int e, float scale, int r, int g) {
    int chunk = (e + FILL_G - 1) / FILL_G;
    int beg = g * chunk, end = min(beg + chunk, e);
    for (int i = beg + threadIdx.x; i < end; i += blockDim.x) {
        unsigned int p = pack[i];
        int d = (int)(p >> 14);
        if ((int)((float)d * scale) == r) {
            int pos = rowptr[d] + (int)(p & 0x3FFFu);
            csr_src[pos] = src[i];
        }
    }
}

// bf16 MFMA gemm: D = A(128xK=128, bf16) x W^T-staged B -> dinv-scaled bf16 out.
// Staging: global_load_lds 16B granules; LDS[row][gp] = global[row][gp ^ (row&7)]
// (pre-swizzled source, linear dest); frag read un-swizzles -> 2-way (free).
// Frags: A row = lane&15, k = ks*32+(lane>>4)*8+j ; B from W^T row n = lane&15.
// C/D (m89-verified): col = lane&15, row = (lane>>4)*4 + reg.

__global__ __launch_bounds__(256) void k_fuse(
        const int* __restrict__ src, const unsigned int* __restrict__ pack,
        const int* __restrict__ rowptr, int* __restrict__ csr_src, int e, float scale,
        const unsigned short* __restrict__ X16, const unsigned short* __restrict__ W1T,
        const float* __restrict__ dinv, unsigned short* __restrict__ H16, int n) {
    __shared__ unsigned short sA[128 * 64];   // 16 KB (rows x 64 k bf16)
    __shared__ unsigned short sB[128 * 64];   // 16 KB (W^T rows x 64 k)

    int t8 = blockIdx.x >> 3, l8 = blockIdx.x & 7;
    int m = t8 % 3, q = t8 / 3;

    if (m < 2) {
        int g = q * 2 + m;
        if (g < FILL_G)
            fill_role(src, pack, rowptr, csr_src, e, scale, l8, g);
        return;
    }

    int bid = q * 8 + l8;
    int row0 = bid * 128;
    if (row0 >= n) return;

    int tid = threadIdx.x;
    int lane = tid & 63;
    int wv = tid >> 6;

    facc4 acc[2][8];
#pragma unroll
    for (int i = 0; i < 2; ++i)
#pragma unroll
        for (int j = 0; j < 8; ++j) acc[i][j] = (facc4)0.f;

    for (int s = 0; s < 2; ++s) {
        if (s) __syncthreads();
        // ---- stage A slab (128 rows x 64 k bf16 = 1024 granules) ----
#pragma unroll
        for (int it = 0; it < 4; ++it) {
            int chunk = it * 4 + wv;
            int L = chunk * 64 + lane;
            int row = L >> 3, gp = L & 7;
            int gsrc = gp ^ (row & 7);
            int grow = min(row0 + row, n - 1);
            const unsigned short* srcp = X16 + (long)grow * 128 + s * 64 + gsrc * 8;
            unsigned short* dstp = sA + chunk * 512;
            __builtin_amdgcn_global_load_lds(
                (const __attribute__((address_space(1))) void*)srcp,
                (__attribute__((address_space(3))) void*)dstp, 16, 0, 0);
        }
        // ---- stage W^T slab (128 rows x 64 k) ----
#pragma unroll
        for (int it = 0; it < 4; ++it) {
            int chunk = it * 4 + wv;
            int L = chunk * 64 + lane;
            int row = L >> 3, gp = L & 7;
            int gsrc = gp ^ (row & 7);
            const unsigned short* srcp = W1T + (long)row * 128 + s * 64 + gsrc * 8;
            unsigned short* dstp = sB + chunk * 512;
            __builtin_amdgcn_global_load_lds(
                (const __attribute__((address_space(1))) void*)srcp,
                (__attribute__((address_space(3))) void*)dstp, 16, 0, 0);
        }
        __syncthreads();

        bfrag8 af[2][2];
#pragma unroll
        for (int mt = 0; mt < 2; ++mt)
#pragma unroll
            for (int ks = 0; ks < 2; ++ks) {
                int r = wv * 32 + mt * 16 + (lane & 15);
                int g = ks * 4 + (lane >> 4);
                af[mt][ks] = *reinterpret_cast<const bfrag8*>(&sA[r * 64 + (g ^ (r & 7)) * 8]);
            }
#pragma unroll
        for (int nt = 0; nt < 8; ++nt) {
            int nr = nt * 16 + (lane & 15);
            bfrag8 b0 = *reinterpret_cast<const bfrag8*>(&sB[nr * 64 + (((lane >> 4)) ^ (nr & 7)) * 8]);
            bfrag8 b1 = *reinterpret_cast<const bfrag8*>(&sB[nr * 64 + ((4 + (lane >> 4)) ^ (nr & 7)) * 8]);
            acc[0][nt] = __builtin_amdgcn_mfma_f32_16x16x32_bf16(af[0][0], b0, acc[0][nt], 0, 0, 0);
            acc[1][nt] = __builtin_amdgcn_mfma_f32_16x16x32_bf16(af[1][0], b0, acc[1][nt], 0, 0, 0);
            acc[0][nt] = __builtin_amdgcn_mfma_f32_16x16x32_bf16(af[0][1], b1, acc[0][nt], 0, 0, 0);
            acc[1][nt] = __builtin_amdgcn_mfma_f32_16x16x32_bf16(af[1][1], b1, acc[1][nt], 0, 0, 0);
        }
    }

    // ---- epilogue: dinv scale + bf16 store ----
#pragma unroll
    for (int mt = 0; mt < 2; ++mt)
#pragma unroll
        for (int reg = 0; reg < 4; ++reg) {
            int r = row0 + wv * 32 + mt * 16 + (lane >> 4) * 4 + reg;
            if (r < n) {
                float dv = dinv[r];
#pragma unroll
                for (int nt = 0; nt < 8; ++nt)
                    H16[(long)r * 128 + nt * 16 + (lane & 15)] =
                        (unsigned short)f2bf(acc[mt][nt][reg] * dv);
            }
        }
}

// ================= MFMA GEMM<64>: zt = dinv * (h16 @ W2) in bf16 =================

__global__ __launch_bounds__(256) void k_gemmM64(const unsigned short* __restrict__ H16,
                                                 const unsigned short* __restrict__ W2T,
                                                 const float* __restrict__ dinv,
                                                 unsigned short* __restrict__ Z16, int n) {
    __shared__ unsigned short sA[128 * 64];   // 16 KB
    __shared__ unsigned short sB[64 * 64];    // 8 KB

    int row0 = blockIdx.x * 128;
    int tid = threadIdx.x;
    int lane = tid & 63;
    int wv = tid >> 6;

    facc4 acc[2][4];
#pragma unroll
    for (int i = 0; i < 2; ++i)
#pragma unroll
        for (int j = 0; j < 4; ++j) acc[i][j] = (facc4)0.f;

    for (int s = 0; s < 2; ++s) {
        if (s) __syncthreads();
#pragma unroll
        for (int it = 0; it < 4; ++it) {
            int chunk = it * 4 + wv;
            int L = chunk * 64 + lane;
            int row = L >> 3, gp = L & 7;
            int gsrc = gp ^ (row & 7);
            int grow = min(row0 + row, n - 1);
            const unsigned short* srcp = H16 + (long)grow * 128 + s * 64 + gsrc * 8;
            unsigned short* dstp = sA + chunk * 512;
            __builtin_amdgcn_global_load_lds(
                (const __attribute__((address_space(1))) void*)srcp,
                (__attribute__((address_space(3))) void*)dstp, 16, 0, 0);
        }
#pragma unroll
        for (int it = 0; it < 2; ++it) {
            int chunk = it * 4 + wv;
            int L = chunk * 64 + lane;
            int row = L >> 3, gp = L & 7;
            int gsrc = gp ^ (row & 7);
            const unsigned short* srcp = W2T + (long)row * 128 + s * 64 + gsrc * 8;
            unsigned short* dstp = sB + chunk * 512;
            __builtin_amdgcn_global_load_lds(
                (const __attribute__((address_space(1))) void*)srcp,
                (__attribute__((address_space(3))) void*)dstp, 16, 0, 0);
        }
        __syncthreads();

        bfrag8 af[2][2];
#pragma unroll
        for (int mt = 0; mt < 2; ++mt)
#pragma unroll
            for (int ks = 0; ks < 2; ++ks) {
                int r = wv * 32 + mt * 16 + (lane & 15);
                int g = ks * 4 + (lane >> 4);
                af[mt][ks] = *reinterpret_cast<const bfrag8*>(&sA[r * 64 + (g ^ (r & 7)) * 8]);
            }
#pragma unroll
        for (int nt = 0; nt < 4; ++nt) {
            int nr = nt * 16 + (lane & 15);
            bfrag8 b0 = *reinterpret_cast<const bfrag8*>(&sB[nr * 64 + (((lane >> 4)) ^ (nr & 7)) * 8]);
            bfrag8 b1 = *reinterpret_cast<const bfrag8*>(&sB[nr * 64 + ((4 + (lane >> 4)) ^ (nr & 7)) * 8]);
            acc[0][nt] = __builtin_amdgcn_mfma_f32_16x16x32_bf16(af[0][0], b0, acc[0][nt], 0, 0, 0);
            acc[1][nt] = __builtin_amdgcn_mfma_f32_16x16x32_bf16(af[1][0], b0, acc[1][nt], 0, 0, 0);
            acc[0][nt] = __builtin_amdgcn_mfma_f32_16x16x32_bf16(af[0][1], b1, acc[0][nt], 0, 0, 0);
            acc[1][nt] = __builtin_amdgcn_mfma_f32_16x16x32_bf16(af[1][1], b1, acc[1][nt], 0, 0, 0);
        }
    }

#pragma unroll
    for (int mt = 0; mt < 2; ++mt)
#pragma unroll
        for (int reg = 0; reg < 4; ++reg) {
            int r = row0 + wv * 32 + mt * 16 + (lane >> 4) * 4 + reg;
            if (r < n) {
                float dv = dinv[r];
#pragma unroll
                for (int nt = 0; nt < 4; ++nt)
                    Z16[(long)r * 64 + nt * 16 + (lane & 15)] =
                        (unsigned short)f2bf(acc[mt][nt][reg] * dv);
            }
        }
}

// ================= pull aggregation from bf16 rows =================
// OB=true -> bf16 output row-major; OB=false -> fp32 output.

template<int C, bool RELU, bool OB>
__global__ void k_gather16(const int* __restrict__ rowptr, const int* __restrict__ csr_src,
                           const float* __restrict__ dinv, const unsigned short* __restrict__ h16,
                           const float* __restrict__ bias, void* __restrict__ outv, int n) {
    const int TPN = C / 8;
    const int RS = C / 8;
    int t = blockIdx.x * blockDim.x + threadIdx.x;
    int node = t / TPN;
    if (node >= n) return;
    int cg = t % TPN;

    const uint4* h4 = reinterpret_cast<const uint4*>(h16);
    float acc[8];
    {
        uint4 u = h4[(long)node * RS + cg];
        acc[0] = bf_lo(u.x); acc[1] = bf_hi(u.x);
        acc[2] = bf_lo(u.y); acc[3] = bf_hi(u.y);
        acc[4] = bf_lo(u.z); acc[5] = bf_hi(u.z);
        acc[6] = bf_lo(u.w); acc[7] = bf_hi(u.w);
    }

    int beg = rowptr[node], end = rowptr[node + 1];
    int e = beg;
    for (; e + 8 <= end; e += 8) {
        int s[8];
#pragma unroll
        for (int q = 0; q < 8; ++q) s[q] = csr_src[e + q];
        uint4 u[8];
#pragma unroll
        for (int q = 0; q < 8; ++q) u[q] = h4[(long)s[q] * RS + cg];
#pragma unroll
        for (int q = 0; q < 8; ++q) {
            acc[0] += bf_lo(u[q].x); acc[1] += bf_hi(u[q].x);
            acc[2] += bf_lo(u[q].y); acc[3] += bf_hi(u[q].y);
            acc[4] += bf_lo(u[q].z); acc[5] += bf_hi(u[q].z);
            acc[6] += bf_lo(u[q].w); acc[7] += bf_hi(u[q].w);
        }
    }
    for (; e < end; ++e) {
        uint4 u = h4[(long)csr_src[e] * RS + cg];
        acc[0] += bf_lo(u.x); acc[1] += bf_hi(u.x);
        acc[2] += bf_lo(u.y); acc[3] += bf_hi(u.y);
        acc[4] += bf_lo(u.z); acc[5] += bf_hi(u.z);
        acc[6] += bf_lo(u.w); acc[7] += bf_hi(u.w);
    }

    float dd = dinv[node];
    int c0 = cg * 8;
    float4 ba = *reinterpret_cast<const float4*>(bias + c0);
    float4 bb = *reinterpret_cast<const float4*>(bias + c0 + 4);
    float o[8];
    o[0] = fmaf(acc[0], dd, ba.x); o[1] = fmaf(acc[1], dd, ba.y);
    o[2] = fmaf(acc[2], dd, ba.z); o[3] = fmaf(acc[3], dd, ba.w);
    o[4] = fmaf(acc[4], dd, bb.x); o[5] = fmaf(acc[5], dd, bb.y);
    o[6] = fmaf(acc[6], dd, bb.z); o[7] = fmaf(acc[7], dd, bb.w);
    if (RELU) {
#pragma unroll
        for (int i = 0; i < 8; ++i) o[i] = fmaxf(o[i], 0.f);
    }
    if (OB) {
        uint4 w;
        w.x = f2bf(o[0]) | (f2bf(o[1]) << 16);
        w.y = f2bf(o[2]) | (f2bf(o[3]) << 16);
        w.z = f2bf(o[4]) | (f2bf(o[5]) << 16);
        w.w = f2bf(o[6]) | (f2bf(o[7]) << 16);
        *reinterpret_cast<uint4*>((unsigned short*)outv + (long)node * C + c0) = w;
    } else {
        float* of = (float*)outv + (long)node * C + c0;
        *reinterpret_cast<float4*>(of) = make_float4(o[0], o[1], o[2], o[3]);
        *reinterpret_cast<float4*>(of + 4) = make_float4(o[4], o[5], o[6], o[7]);
    }
}

// ================= decode (fp32 z) =================

__global__ void k_decode(const int* __restrict__ ia, const int* __restrict__ ib,
                         const float* __restrict__ z, float* __restrict__ out, int m) {
    int t = blockIdx.x * blockDim.x + threadIdx.x;
    int k = t / 16;
    if (k >= m) return;
    int c = (t & 15) * 4;
    int a = ia[k], b = ib[k];
    float4 va = *reinterpret_cast<const float4*>(z + (long)a * 64 + c);
    float4 vb = *reinterpret_cast<const float4*>(z + (long)b * 64 + c);
    float dot = va.x * vb.x + va.y * vb.y + va.z * vb.z + va.w * vb.w;
    dot += __shfl_xor(dot, 8);
    dot += __shfl_xor(dot, 4);
    dot += __shfl_xor(dot, 2);
    dot += __shfl_xor(dot, 1);
    if ((t & 15) == 0) out[k] = dot;
}

// ================= launcher =================

extern "C" void kernel_launch(void* const* d_in, const int* in_sizes, int n_in,
                              void* d_out, int out_size, void* d_ws, size_t ws_size,
                              hipStream_t stream) {
    const float* x  = (const float*)d_in[0];
    const int*   ei = (const int*)d_in[1];
    const int*   el = (const int*)d_in[2];
    const float* W1 = (const float*)d_in[3];
    const float* b1 = (const float*)d_in[4];
    const float* W2 = (const float*)d_in[5];
    const float* b2 = (const float*)d_in[6];
    float* out = (float*)d_out;

    const int N = in_sizes[0] / 128;
    const int E = in_sizes[1] / 2;
    const int L = out_size;

    const int* src = ei;
    const int* dst = ei + E;
    const int* la  = el;
    const int* lb  = el + L;

    char* wsb = (char*)d_ws;

    // region A: bytes [0, N*512)
    unsigned short* ht16 = (unsigned short*)wsb;                       // N*128 bf16 (k_fuse out)
    unsigned short* zt16 = (unsigned short*)wsb;                       // N*64 bf16 (overlay, ht16 dead)
    float*          zout = (float*)(wsb + (size_t)N * 128);            // N*64 f32

    // region B: bytes [N*512, N*1024)
    unsigned int*   pack = (unsigned int*)(wsb + (size_t)N * 512);     // E u32 (dies end of k_fuse)
    unsigned short* h16  = (unsigned short*)(wsb + (size_t)N * 512);   // N*128 bf16 (gather128 out)
    unsigned short* x16  = (unsigned short*)(wsb + (size_t)N * 512 + (size_t)N * 256);  // N*128 bf16

    int*   csr_src = (int*)(wsb + (size_t)N * 1024);                   // E
    int*   cnt     = csr_src + E;                                      // N
    int*   rowptr  = cnt + N;                                          // N+1
    float* dinv    = (float*)(rowptr + N + 1);                         // N
    int*   part    = (int*)(dinv + N);                                 // SCP
    unsigned short* w1t = (unsigned short*)(part + SCP);               // 128*128
    unsigned short* w2t = w1t + 128 * 128;                             // 64*128

    auto cdiv = [](long a, long b) { return (int)((a + b - 1) / b); };

    // ---- convert inputs to bf16 (x row-major, W transposed) ----
    int nx8 = N * 16;
    k_cvt<<<cdiv((long)nx8 + 128 * 128 + 128 * 64, 256), 256, 0, stream>>>(
        x, W1, W2, x16, w1t, w2t, nx8);

    // ---- CSR build + normalization ----
    hipMemsetAsync(cnt, 0, (size_t)N * sizeof(int), stream);
    k_count <<<cdiv(E, 256), 256, 0, stream>>>(dst, cnt, pack, E);
    k_scan_a<<<SCP / 256, 256, 0, stream>>>(cnt, part, N);
    k_scan_b<<<1, SCP, 0, stream>>>(part);
    k_scan_c<<<SCP / 256, 256, 0, stream>>>(cnt, part, rowptr, dinv, N);

    // ---- fused: CSR fill || MFMA layer-1 GEMM (bf16 h-tilde out) ----
    k_fuse<<<294 * 8, 256, 0, stream>>>(src, pack, rowptr, csr_src, E, 8.0f / (float)N,
                                        x16, w1t, dinv, ht16, N);

    // ---- layer 1 aggregation: h = relu(agg) + b1 (bf16 out) ----
    k_gather16<128, true, true><<<cdiv((long)N * 16, 256), 256, 0, stream>>>(
        rowptr, csr_src, dinv, ht16, b1, h16, N);

    // ---- layer 2: z-tilde = dinv*(h @ W2) via MFMA (bf16 out), then aggregate ----
    k_gemmM64<<<cdiv(N, 128), 256, 0, stream>>>(h16, w2t, dinv, zt16, N);
    k_gather16<64, false, false><<<cdiv((long)N * 8, 256), 256, 0, stream>>>(
        rowptr, csr_src, dinv, zt16, b2, zout, N);

    // ---- decode ----
    k_decode<<<cdiv((long)L * 16, 256), 256, 0, stream>>>(la, lb, zout, out, L);
}